// Round 1
// baseline (526.281 us; speedup 1.0000x reference)
//
#include <hip/hip_runtime.h>
#include <math.h>

// Problem constants
#define CCH   640          // channels
#define MM    25           // m = 5*5 spatial
#define NB    4096         // query batch
#define WSR   25           // way*shot prototype rows
#define ROWF  16000        // CCH*MM floats per row
#define SLAB  (NB*CCH)     // 2,621,440 floats = one output slab (per w)

// ---------------------------------------------------------------------------
// rowmean: one block per row; LDS-stage the 64KB row coalesced, then per-c sum
// ---------------------------------------------------------------------------
__global__ __launch_bounds__(256) void rowmean_k(const float* __restrict__ src,
                                                 float* __restrict__ dst) {
  int b = blockIdx.x;
  __shared__ __align__(16) float qb[ROWF];
  const float4* row4 = (const float4*)(src + (size_t)b * ROWF);
  for (int idx = threadIdx.x; idx < ROWF/4; idx += 256)
    ((float4*)qb)[idx] = row4[idx];
  __syncthreads();
  for (int c = threadIdx.x; c < CCH; c += 256) {
    float s = 0.f;
    #pragma unroll
    for (int m = 0; m < MM; ++m) s += qb[c*MM + m];
    dst[(size_t)b*CCH + c] = s * (1.f/25.f);
  }
}

// ---------------------------------------------------------------------------
// GEMM: out = 1 + tanh( (A @ W^T - rm) * rsqrt(rv+eps) * g + b )
// A: M x 640, W: 640 x 640 row-major (y[i,j] = sum_k A[i,k]*W[j,k])
// 64x64 tile, 256 threads, 4x4 per thread, BK=16 LDS staging.
// ---------------------------------------------------------------------------
__global__ __launch_bounds__(256) void gemm_bn_tanh_k(
    const float* __restrict__ A, const float* __restrict__ W,
    const float* __restrict__ gg, const float* __restrict__ bb,
    const float* __restrict__ rm, const float* __restrict__ rv,
    int M, float* __restrict__ out) {
  __shared__ __align__(16) float As[16][68];   // [k][row], pad stride 68
  __shared__ __align__(16) float Bs[16][68];   // [k][col]
  const int tid = threadIdx.x;
  const int i0 = blockIdx.x * 64;
  const int j0 = blockIdx.y * 64;
  const int lr = tid >> 2;          // 0..63  (tile row / tile col for load)
  const int lk = (tid & 3) << 2;    // 0,4,8,12
  const int tm = tid >> 4;          // 0..15 -> rows tm*4..tm*4+3
  const int tn = tid & 15;          // 0..15 -> cols tn*4..tn*4+3
  float acc[4][4] = {};
  for (int kt = 0; kt < CCH; kt += 16) {
    float4 av = make_float4(0.f, 0.f, 0.f, 0.f);
    if (i0 + lr < M)
      av = *(const float4*)(A + (size_t)(i0 + lr)*CCH + kt + lk);
    float4 bv = *(const float4*)(W + (size_t)(j0 + lr)*CCH + kt + lk);
    As[lk+0][lr] = av.x; As[lk+1][lr] = av.y; As[lk+2][lr] = av.z; As[lk+3][lr] = av.w;
    Bs[lk+0][lr] = bv.x; Bs[lk+1][lr] = bv.y; Bs[lk+2][lr] = bv.z; Bs[lk+3][lr] = bv.w;
    __syncthreads();
    #pragma unroll
    for (int k = 0; k < 16; ++k) {
      float4 a4 = *(const float4*)&As[k][tm << 2];
      float4 b4 = *(const float4*)&Bs[k][tn << 2];
      float ar[4] = {a4.x, a4.y, a4.z, a4.w};
      float br[4] = {b4.x, b4.y, b4.z, b4.w};
      #pragma unroll
      for (int r = 0; r < 4; ++r)
        #pragma unroll
        for (int c = 0; c < 4; ++c)
          acc[r][c] = fmaf(ar[r], br[c], acc[r][c]);
    }
    __syncthreads();
  }
  // BN + tanh epilogue
  float sc[4], sh[4];
  #pragma unroll
  for (int c = 0; c < 4; ++c) {
    int j = j0 + (tn << 2) + c;
    float s = rsqrtf(rv[j] + 1e-5f) * gg[j];
    sc[c] = s;
    sh[c] = bb[j] - rm[j] * s;
  }
  #pragma unroll
  for (int r = 0; r < 4; ++r) {
    int row = i0 + (tm << 2) + r;
    if (row < M) {
      float4 o;
      o.x = 1.f + tanhf(fmaf(acc[r][0], sc[0], sh[0]));
      o.y = 1.f + tanhf(fmaf(acc[r][1], sc[1], sh[1]));
      o.z = 1.f + tanhf(fmaf(acc[r][2], sc[2], sh[2]));
      o.w = 1.f + tanhf(fmaf(acc[r][3], sc[3], sh[3]));
      *(float4*)(out + (size_t)row*CCH + j0 + (tn << 2)) = o;
    }
  }
}

// ---------------------------------------------------------------------------
// pcd: per row b: x = src[b]*scl[b] (gate), pooled = [max_c, mean_c] (2,5,5),
// v = sigmoid(conv3x3(pooled)+cb) (25), ndist[b,c] = -sum_m (x[c,m]-v[m])^2
// ---------------------------------------------------------------------------
__global__ __launch_bounds__(256) void pcd_k(const float* __restrict__ src,
    const float* __restrict__ scl, const float* __restrict__ cw,
    const float* __restrict__ cbp, float* __restrict__ ndist) {
  int b = blockIdx.x;
  __shared__ __align__(16) float qb[ROWF];
  __shared__ float sc[CCH];
  __shared__ float red[4][2][25];
  __shared__ float vbuf[25];
  const float4* row4 = (const float4*)(src + (size_t)b * ROWF);
  for (int idx = threadIdx.x; idx < ROWF/4; idx += 256)
    ((float4*)qb)[idx] = row4[idx];
  for (int c = threadIdx.x; c < CCH; c += 256)
    sc[c] = scl[(size_t)b*CCH + c];
  __syncthreads();

  float lmax[25], lsum[25];
  #pragma unroll
  for (int p = 0; p < 25; ++p) { lmax[p] = -3.4e38f; lsum[p] = 0.f; }
  for (int c = threadIdx.x; c < CCH; c += 256) {
    float s = sc[c];
    #pragma unroll
    for (int p = 0; p < 25; ++p) {
      float v = qb[c*25 + p] * s;
      lmax[p] = fmaxf(lmax[p], v);
      lsum[p] += v;
    }
  }
  // wave(64) butterfly-free down-reduce
  #pragma unroll
  for (int off = 32; off > 0; off >>= 1) {
    #pragma unroll
    for (int p = 0; p < 25; ++p) {
      lmax[p] = fmaxf(lmax[p], __shfl_down(lmax[p], off));
      lsum[p] += __shfl_down(lsum[p], off);
    }
  }
  int lane = threadIdx.x & 63, wv = threadIdx.x >> 6;
  if (lane == 0) {
    #pragma unroll
    for (int p = 0; p < 25; ++p) { red[wv][0][p] = lmax[p]; red[wv][1][p] = lsum[p]; }
  }
  __syncthreads();
  if (threadIdx.x < 25) {
    int p = threadIdx.x;
    float mx = red[0][0][p], sm = red[0][1][p];
    #pragma unroll
    for (int w = 1; w < 4; ++w) { mx = fmaxf(mx, red[w][0][p]); sm += red[w][1][p]; }
    red[0][0][p] = mx;                 // pooled channel 0: max
    red[0][1][p] = sm * (1.f/640.f);   // pooled channel 1: mean
  }
  __syncthreads();
  if (threadIdx.x < 25) {
    int h = threadIdx.x / 5, w_ = threadIdx.x % 5;
    float y = cbp[0];
    #pragma unroll
    for (int ci = 0; ci < 2; ++ci)
      #pragma unroll
      for (int kh = 0; kh < 3; ++kh)
        #pragma unroll
        for (int kw = 0; kw < 3; ++kw) {
          int hh = h + kh - 1, ww = w_ + kw - 1;
          if (hh >= 0 && hh < 5 && ww >= 0 && ww < 5)
            y += red[0][ci][hh*5 + ww] * cw[ci*9 + kh*3 + kw];
        }
    vbuf[threadIdx.x] = 1.f / (1.f + expf(-y));
  }
  __syncthreads();
  for (int c = threadIdx.x; c < CCH; c += 256) {
    float s = sc[c], d = 0.f;
    #pragma unroll
    for (int p = 0; p < 25; ++p) {
      float t = fmaf(qb[c*25 + p], s, -vbuf[p]);
      d = fmaf(t, t, d);
    }
    ndist[(size_t)b*CCH + c] = -d;     // negated: feeds s_block(-dist) GEMM
  }
}

// ---------------------------------------------------------------------------
// combine: out[w,b,c] = 0.5*wprt[w,c] + 0.5*wqry[b,c]. wqry lives in slab 3 of
// d_out, so do the 24 other slabs first, then slab 3 in place (elementwise).
// ---------------------------------------------------------------------------
__global__ __launch_bounds__(256) void combine24_k(const float* __restrict__ wq,
    const float* __restrict__ wp, float* __restrict__ out) {
  const size_t S4 = (size_t)SLAB / 4;
  size_t idx = (size_t)blockIdx.x * 256 + threadIdx.x;  // float4 index over 24 slabs
  int slot = (int)(idx / S4);
  size_t rem = idx - (size_t)slot * S4;
  int w = (slot < 3) ? slot : slot + 1;                 // skip slab 3 (w_qry)
  int c = (int)((rem * 4) % CCH);
  float4 q = ((const float4*)wq)[rem];
  float4 p = *(const float4*)(wp + w*CCH + c);
  float4 o;
  o.x = 0.5f*(q.x + p.x); o.y = 0.5f*(q.y + p.y);
  o.z = 0.5f*(q.z + p.z); o.w = 0.5f*(q.w + p.w);
  ((float4*)out)[(size_t)w * S4 + rem] = o;
}

__global__ __launch_bounds__(256) void combine3_k(const float* __restrict__ wp,
                                                  float* __restrict__ out) {
  const size_t S4 = (size_t)SLAB / 4;
  size_t rem = (size_t)blockIdx.x * 256 + threadIdx.x;
  int c = (int)((rem * 4) % CCH);
  float4* ptr = (float4*)out + 3 * S4 + rem;
  float4 q = *ptr;                                      // w_qry written this call
  float4 p = *(const float4*)(wp + 3*CCH + c);
  float4 o;
  o.x = 0.5f*(q.x + p.x); o.y = 0.5f*(q.y + p.y);
  o.z = 0.5f*(q.z + p.z); o.w = 0.5f*(q.w + p.w);
  *ptr = o;
}

// ---------------------------------------------------------------------------
extern "C" void kernel_launch(void* const* d_in, const int* in_sizes, int n_in,
                              void* d_out, int out_size, void* d_ws, size_t ws_size,
                              hipStream_t stream) {
  const float* spt    = (const float*)d_in[0];
  const float* qry    = (const float*)d_in[1];
  const float* W_p    = (const float*)d_in[2];
  const float* g_p    = (const float*)d_in[3];
  const float* b_p    = (const float*)d_in[4];
  const float* rm_p   = (const float*)d_in[5];
  const float* rv_p   = (const float*)d_in[6];
  const float* W_q    = (const float*)d_in[7];
  const float* g_q    = (const float*)d_in[8];
  const float* b_q    = (const float*)d_in[9];
  const float* rm_q   = (const float*)d_in[10];
  const float* rv_q   = (const float*)d_in[11];
  const float* W_prt  = (const float*)d_in[12];
  const float* g_prt  = (const float*)d_in[13];
  const float* b_prt  = (const float*)d_in[14];
  const float* rm_prt = (const float*)d_in[15];
  const float* rv_prt = (const float*)d_in[16];
  const float* W_qs   = (const float*)d_in[17];
  const float* g_qs   = (const float*)d_in[18];
  const float* b_qs   = (const float*)d_in[19];
  const float* rm_qs  = (const float*)d_in[20];
  const float* rv_qs  = (const float*)d_in[21];
  const float* cw_p   = (const float*)d_in[22];
  const float* cb_p   = (const float*)d_in[23];
  const float* cw_q   = (const float*)d_in[24];
  const float* cb_q   = (const float*)d_in[25];

  float* outp = (float*)d_out;
  // big intermediates staged in d_out slabs (each fully rewritten every call)
  float* qmean  = outp + 0 * (size_t)SLAB;
  float* qg     = outp + 1 * (size_t)SLAB;
  float* ndist2 = outp + 2 * (size_t)SLAB;
  float* wqry   = outp + 3 * (size_t)SLAB;
  // small prototype-path buffers in workspace (256 KB)
  float* ws     = (float*)d_ws;
  float* pmean  = ws;
  float* sbuf   = ws + 16000;
  float* ndist1 = ws + 32000;
  float* wprt   = ws + 48000;

  dim3 blk(256);
  // ---- prototype path (25 rows, tiny) ----
  rowmean_k<<<WSR, blk, 0, stream>>>(spt, pmean);
  gemm_bn_tanh_k<<<dim3(1, CCH/64), blk, 0, stream>>>(pmean, W_p, g_p, b_p, rm_p, rv_p, WSR, sbuf);
  pcd_k<<<WSR, blk, 0, stream>>>(spt, sbuf, cw_p, cb_p, ndist1);
  gemm_bn_tanh_k<<<dim3(1, CCH/64), blk, 0, stream>>>(ndist1, W_prt, g_prt, b_prt, rm_prt, rv_prt, WSR, wprt);
  // ---- query path (4096 rows) ----
  rowmean_k<<<NB, blk, 0, stream>>>(qry, qmean);
  gemm_bn_tanh_k<<<dim3(NB/64, CCH/64), blk, 0, stream>>>(qmean, W_q, g_q, b_q, rm_q, rv_q, NB, qg);
  pcd_k<<<NB, blk, 0, stream>>>(qry, qg, cw_q, cb_q, ndist2);
  gemm_bn_tanh_k<<<dim3(NB/64, CCH/64), blk, 0, stream>>>(ndist2, W_qs, g_qs, b_qs, rm_qs, rv_qs, NB, wqry);
  // ---- combine: 24 slabs then slab 3 in place ----
  combine24_k<<<(24 * (SLAB/4)) / 256, blk, 0, stream>>>(wqry, wprt, outp);
  combine3_k<<<(SLAB/4) / 256, blk, 0, stream>>>(wprt, outp);
}

// Round 2
// 408.004 us; speedup vs baseline: 1.2899x; 1.2899x over previous
//
#include <hip/hip_runtime.h>
#include <math.h>

// Problem constants
#define CCH   640          // channels
#define MM    25           // m = 5*5 spatial
#define NB    4096         // query batch
#define WSR   25           // way*shot prototype rows
#define ROWF  16000        // CCH*MM floats per row
#define SLAB  (NB*CCH)     // 2,621,440 floats = one output slab (per w)

static __device__ __forceinline__ void load4(float* dst, const float* p) {
  // 4B-aligned 16B load; gfx950 supports unaligned dwordx4
  __builtin_memcpy(dst, p, 16);
}

// ---------------------------------------------------------------------------
// rowmean: one thread per (b,c); 25 dense floats per thread; no LDS.
// ---------------------------------------------------------------------------
__global__ __launch_bounds__(256) void rowmean_k(const float* __restrict__ src,
                                                 float* __restrict__ dst, int n) {
  int idx = blockIdx.x * 256 + threadIdx.x;   // idx = b*CCH + c
  if (idx >= n) return;
  int b = idx / CCH, c = idx - b * CCH;
  const float* p = src + (size_t)b * ROWF + c * MM;
  float s = 0.f;
  float v[4];
  #pragma unroll
  for (int j = 0; j < 6; ++j) {
    load4(v, p + 4*j);
    s += (v[0] + v[1]) + (v[2] + v[3]);
  }
  s += p[24];
  dst[idx] = s * (1.f/25.f);
}

// ---------------------------------------------------------------------------
// GEMM: out = 1 + tanh( (A @ W^T - rm) * rsqrt(rv+eps) * g + b )
// ---------------------------------------------------------------------------
__global__ __launch_bounds__(256) void gemm_bn_tanh_k(
    const float* __restrict__ A, const float* __restrict__ W,
    const float* __restrict__ gg, const float* __restrict__ bb,
    const float* __restrict__ rm, const float* __restrict__ rv,
    int M, float* __restrict__ out) {
  __shared__ __align__(16) float As[16][68];
  __shared__ __align__(16) float Bs[16][68];
  const int tid = threadIdx.x;
  const int i0 = blockIdx.x * 64;
  const int j0 = blockIdx.y * 64;
  const int lr = tid >> 2;
  const int lk = (tid & 3) << 2;
  const int tm = tid >> 4;
  const int tn = tid & 15;
  float acc[4][4] = {};
  for (int kt = 0; kt < CCH; kt += 16) {
    float4 av = make_float4(0.f, 0.f, 0.f, 0.f);
    if (i0 + lr < M)
      av = *(const float4*)(A + (size_t)(i0 + lr)*CCH + kt + lk);
    float4 bv = *(const float4*)(W + (size_t)(j0 + lr)*CCH + kt + lk);
    As[lk+0][lr] = av.x; As[lk+1][lr] = av.y; As[lk+2][lr] = av.z; As[lk+3][lr] = av.w;
    Bs[lk+0][lr] = bv.x; Bs[lk+1][lr] = bv.y; Bs[lk+2][lr] = bv.z; Bs[lk+3][lr] = bv.w;
    __syncthreads();
    #pragma unroll
    for (int k = 0; k < 16; ++k) {
      float4 a4 = *(const float4*)&As[k][tm << 2];
      float4 b4 = *(const float4*)&Bs[k][tn << 2];
      float ar[4] = {a4.x, a4.y, a4.z, a4.w};
      float br[4] = {b4.x, b4.y, b4.z, b4.w};
      #pragma unroll
      for (int r = 0; r < 4; ++r)
        #pragma unroll
        for (int c = 0; c < 4; ++c)
          acc[r][c] = fmaf(ar[r], br[c], acc[r][c]);
    }
    __syncthreads();
  }
  float sc[4], sh[4];
  #pragma unroll
  for (int c = 0; c < 4; ++c) {
    int j = j0 + (tn << 2) + c;
    float s = rsqrtf(rv[j] + 1e-5f) * gg[j];
    sc[c] = s;
    sh[c] = bb[j] - rm[j] * s;
  }
  #pragma unroll
  for (int r = 0; r < 4; ++r) {
    int row = i0 + (tm << 2) + r;
    if (row < M) {
      float4 o;
      o.x = 1.f + tanhf(fmaf(acc[r][0], sc[0], sh[0]));
      o.y = 1.f + tanhf(fmaf(acc[r][1], sc[1], sh[1]));
      o.z = 1.f + tanhf(fmaf(acc[r][2], sc[2], sh[2]));
      o.w = 1.f + tanhf(fmaf(acc[r][3], sc[3], sh[3]));
      *(float4*)(out + (size_t)row*CCH + j0 + (tn << 2)) = o;
    }
  }
}

// ---------------------------------------------------------------------------
// pcd: register-resident rewrite. 320 threads; thread t owns channels t, t+320
// (50 gated floats in VGPRs). Pool via LDS-transpose reduce (32KB), conv in
// 25 threads, distance from registers. One global pass over the row.
// ---------------------------------------------------------------------------
__global__ __launch_bounds__(320, 4) void pcd_k(const float* __restrict__ src,
    const float* __restrict__ scl, const float* __restrict__ cw,
    const float* __restrict__ cbp, float* __restrict__ ndist) {
  const int b = blockIdx.x;
  const int t = threadIdx.x;
  __shared__ float xp[320 * MM];     // 32000 B transpose buffer
  __shared__ float part[10][MM];
  __shared__ float pooled[2][MM];
  __shared__ float vbuf[MM];

  const float* row = src + (size_t)b * ROWF;
  const float sc0 = scl[(size_t)b*CCH + t];
  const float sc1 = scl[(size_t)b*CCH + t + 320];

  float x0[MM], x1[MM];
  {
    const float* p0 = row + t * MM;
    const float* p1 = row + (t + 320) * MM;
    float v[4];
    #pragma unroll
    for (int j = 0; j < 6; ++j) {
      load4(v, p0 + 4*j);
      x0[4*j+0] = v[0]*sc0; x0[4*j+1] = v[1]*sc0; x0[4*j+2] = v[2]*sc0; x0[4*j+3] = v[3]*sc0;
    }
    x0[24] = p0[24] * sc0;
    #pragma unroll
    for (int j = 0; j < 6; ++j) {
      load4(v, p1 + 4*j);
      x1[4*j+0] = v[0]*sc1; x1[4*j+1] = v[1]*sc1; x1[4*j+2] = v[2]*sc1; x1[4*j+3] = v[3]*sc1;
    }
    x1[24] = p1[24] * sc1;
  }

  // ---- pooled max ----
  #pragma unroll
  for (int p = 0; p < MM; ++p) xp[t*MM + p] = fmaxf(x0[p], x1[p]);
  __syncthreads();
  if (t < 250) {
    int g = t / MM, p = t - g * MM;   // lanes: p fastest -> stride-25 reads, ~conflict-free
    float m = -3.4e38f;
    #pragma unroll
    for (int k = 0; k < 32; ++k) m = fmaxf(m, xp[(g*32 + k)*MM + p]);
    part[g][p] = m;
  }
  __syncthreads();
  if (t < MM) {
    float m = -3.4e38f;
    #pragma unroll
    for (int g = 0; g < 10; ++g) m = fmaxf(m, part[g][t]);
    pooled[0][t] = m;
  }
  // ---- pooled mean (reuse xp; pooled[0] write above is to a different buffer,
  //      but xp rewrite must wait until all step-2 reads done) ----
  __syncthreads();
  #pragma unroll
  for (int p = 0; p < MM; ++p) xp[t*MM + p] = x0[p] + x1[p];
  __syncthreads();
  if (t < 250) {
    int g = t / MM, p = t - g * MM;
    float s = 0.f;
    #pragma unroll
    for (int k = 0; k < 32; ++k) s += xp[(g*32 + k)*MM + p];
    part[g][p] = s;
  }
  __syncthreads();
  if (t < MM) {
    float s = 0.f;
    #pragma unroll
    for (int g = 0; g < 10; ++g) s += part[g][t];
    pooled[1][t] = s * (1.f/640.f);
  }
  __syncthreads();
  // ---- 3x3 conv + sigmoid (25 threads) ----
  if (t < MM) {
    int h = t / 5, w_ = t % 5;
    float y = cbp[0];
    #pragma unroll
    for (int ci = 0; ci < 2; ++ci)
      #pragma unroll
      for (int kh = 0; kh < 3; ++kh)
        #pragma unroll
        for (int kw = 0; kw < 3; ++kw) {
          int hh = h + kh - 1, ww = w_ + kw - 1;
          if (hh >= 0 && hh < 5 && ww >= 0 && ww < 5)
            y += pooled[ci][hh*5 + ww] * cw[ci*9 + kh*3 + kw];
        }
    vbuf[t] = 1.f / (1.f + expf(-y));
  }
  __syncthreads();
  // ---- distance from registers ----
  float d0 = 0.f, d1 = 0.f;
  #pragma unroll
  for (int p = 0; p < MM; ++p) {
    float v = vbuf[p];
    float a = x0[p] - v; d0 = fmaf(a, a, d0);
    float e = x1[p] - v; d1 = fmaf(e, e, d1);
  }
  ndist[(size_t)b*CCH + t]       = -d0;
  ndist[(size_t)b*CCH + t + 320] = -d1;
}

// ---------------------------------------------------------------------------
// combine: out[w,b,c] = 0.5*wprt[w,c] + 0.5*wqry[b,c].
// ---------------------------------------------------------------------------
__global__ __launch_bounds__(256) void combine24_k(const float* __restrict__ wq,
    const float* __restrict__ wp, float* __restrict__ out) {
  const size_t S4 = (size_t)SLAB / 4;
  size_t idx = (size_t)blockIdx.x * 256 + threadIdx.x;
  int slot = (int)(idx / S4);
  size_t rem = idx - (size_t)slot * S4;
  int w = (slot < 3) ? slot : slot + 1;                 // skip slab 3 (w_qry)
  int c = (int)((rem * 4) % CCH);
  float4 q = ((const float4*)wq)[rem];
  float4 p = *(const float4*)(wp + w*CCH + c);
  float4 o;
  o.x = 0.5f*(q.x + p.x); o.y = 0.5f*(q.y + p.y);
  o.z = 0.5f*(q.z + p.z); o.w = 0.5f*(q.w + p.w);
  ((float4*)out)[(size_t)w * S4 + rem] = o;
}

__global__ __launch_bounds__(256) void combine3_k(const float* __restrict__ wp,
                                                  float* __restrict__ out) {
  const size_t S4 = (size_t)SLAB / 4;
  size_t rem = (size_t)blockIdx.x * 256 + threadIdx.x;
  int c = (int)((rem * 4) % CCH);
  float4* ptr = (float4*)out + 3 * S4 + rem;
  float4 q = *ptr;
  float4 p = *(const float4*)(wp + 3*CCH + c);
  float4 o;
  o.x = 0.5f*(q.x + p.x); o.y = 0.5f*(q.y + p.y);
  o.z = 0.5f*(q.z + p.z); o.w = 0.5f*(q.w + p.w);
  *ptr = o;
}

// ---------------------------------------------------------------------------
extern "C" void kernel_launch(void* const* d_in, const int* in_sizes, int n_in,
                              void* d_out, int out_size, void* d_ws, size_t ws_size,
                              hipStream_t stream) {
  const float* spt    = (const float*)d_in[0];
  const float* qry    = (const float*)d_in[1];
  const float* W_p    = (const float*)d_in[2];
  const float* g_p    = (const float*)d_in[3];
  const float* b_p    = (const float*)d_in[4];
  const float* rm_p   = (const float*)d_in[5];
  const float* rv_p   = (const float*)d_in[6];
  const float* W_q    = (const float*)d_in[7];
  const float* g_q    = (const float*)d_in[8];
  const float* b_q    = (const float*)d_in[9];
  const float* rm_q   = (const float*)d_in[10];
  const float* rv_q   = (const float*)d_in[11];
  const float* W_prt  = (const float*)d_in[12];
  const float* g_prt  = (const float*)d_in[13];
  const float* b_prt  = (const float*)d_in[14];
  const float* rm_prt = (const float*)d_in[15];
  const float* rv_prt = (const float*)d_in[16];
  const float* W_qs   = (const float*)d_in[17];
  const float* g_qs   = (const float*)d_in[18];
  const float* b_qs   = (const float*)d_in[19];
  const float* rm_qs  = (const float*)d_in[20];
  const float* rv_qs  = (const float*)d_in[21];
  const float* cw_p   = (const float*)d_in[22];
  const float* cb_p   = (const float*)d_in[23];
  const float* cw_q   = (const float*)d_in[24];
  const float* cb_q   = (const float*)d_in[25];

  float* outp = (float*)d_out;
  float* qmean  = outp + 0 * (size_t)SLAB;
  float* qg     = outp + 1 * (size_t)SLAB;
  float* ndist2 = outp + 2 * (size_t)SLAB;
  float* wqry   = outp + 3 * (size_t)SLAB;
  float* ws     = (float*)d_ws;
  float* pmean  = ws;
  float* sbuf   = ws + 16000;
  float* ndist1 = ws + 32000;
  float* wprt   = ws + 48000;

  dim3 blk(256);
  dim3 blkp(320);
  // ---- prototype path (25 rows, tiny) ----
  rowmean_k<<<(WSR*CCH + 255)/256, blk, 0, stream>>>(spt, pmean, WSR*CCH);
  gemm_bn_tanh_k<<<dim3(1, CCH/64), blk, 0, stream>>>(pmean, W_p, g_p, b_p, rm_p, rv_p, WSR, sbuf);
  pcd_k<<<WSR, blkp, 0, stream>>>(spt, sbuf, cw_p, cb_p, ndist1);
  gemm_bn_tanh_k<<<dim3(1, CCH/64), blk, 0, stream>>>(ndist1, W_prt, g_prt, b_prt, rm_prt, rv_prt, WSR, wprt);
  // ---- query path (4096 rows) ----
  rowmean_k<<<(NB*CCH)/256, blk, 0, stream>>>(qry, qmean, NB*CCH);
  gemm_bn_tanh_k<<<dim3(NB/64, CCH/64), blk, 0, stream>>>(qmean, W_q, g_q, b_q, rm_q, rv_q, NB, qg);
  pcd_k<<<NB, blkp, 0, stream>>>(qry, qg, cw_q, cb_q, ndist2);
  gemm_bn_tanh_k<<<dim3(NB/64, CCH/64), blk, 0, stream>>>(ndist2, W_qs, g_qs, b_qs, rm_qs, rv_qs, NB, wqry);
  // ---- combine ----
  combine24_k<<<(24 * (SLAB/4)) / 256, blk, 0, stream>>>(wqry, wprt, outp);
  combine3_k<<<(SLAB/4) / 256, blk, 0, stream>>>(wprt, outp);
}